// Round 2
// baseline (509.650 us; speedup 1.0000x reference)
//
#include <hip/hip_runtime.h>

// Problem constants (must match reference setup_inputs / RADIUS)
#define BATCH 64
#define HH    512
#define WW    512
#define CC    6
#define RR    2
#define COUT  4                  // C - 2
#define BLOCKS_PER_SAMPLE 128    // 128 blocks * 256 thr * 8 float4 = 512*512 pixels
#define F4_PER_THREAD 8

__global__ __launch_bounds__(256)
void values_around_pump_kernel(const float* __restrict__ fields,
                               const int*   __restrict__ pump_idx,
                               float4*      __restrict__ out)
{
    const int b   = blockIdx.x / BLOCKS_PER_SAMPLE;
    const int bis = blockIdx.x % BLOCKS_PER_SAMPLE;
    const int tid = threadIdx.x;

    __shared__ float4 mean_s;

    // ---- wave 0: load 5x5 window (channels 2..5), reduce, divide by 25 ----
    if (tid < 64) {
        float s0 = 0.f, s1 = 0.f, s2 = 0.f, s3 = 0.f;
        if (tid < 25) {
            const int py = pump_idx[2 * b + 0];
            const int px = pump_idx[2 * b + 1];
            const int dy = tid / 5 - RR;
            const int dx = tid % 5 - RR;
            const size_t pix = ((size_t)b * HH + (size_t)(py + dy)) * WW + (size_t)(px + dx);
            const float* p = fields + pix * CC + 2;   // channels [2:6], contiguous
            s0 = p[0]; s1 = p[1]; s2 = p[2]; s3 = p[3];
        }
        // full-wave (64-lane) butterfly-down reduce; lanes 25..63 contribute 0
        #pragma unroll
        for (int off = 32; off >= 1; off >>= 1) {
            s0 += __shfl_down(s0, off);
            s1 += __shfl_down(s1, off);
            s2 += __shfl_down(s2, off);
            s3 += __shfl_down(s3, off);
        }
        if (tid == 0) {
            const float inv = 1.0f / 25.0f;
            mean_s = make_float4(s0 * inv, s1 * inv, s2 * inv, s3 * inv);
        }
    }
    __syncthreads();
    const float4 m = mean_s;

    // ---- broadcast-fill: 8 coalesced float4 stores per thread ----
    float4* o = out + (size_t)b * ((size_t)HH * WW)
                    + (size_t)bis * (256 * F4_PER_THREAD);
    #pragma unroll
    for (int j = 0; j < F4_PER_THREAD; ++j) {
        o[tid + j * 256] = m;
    }
}

extern "C" void kernel_launch(void* const* d_in, const int* in_sizes, int n_in,
                              void* d_out, int out_size, void* d_ws, size_t ws_size,
                              hipStream_t stream)
{
    const float* fields   = (const float*)d_in[0];
    const int*   pump_idx = (const int*)d_in[1];
    float4*      out      = (float4*)d_out;   // (B, H, W, 4) fp32, 16B-aligned

    const int grid = BATCH * BLOCKS_PER_SAMPLE;  // 8192 blocks
    values_around_pump_kernel<<<grid, 256, 0, stream>>>(fields, pump_idx, out);
}